// Round 2
// baseline (162.509 us; speedup 1.0000x reference)
//
#include <hip/hip_runtime.h>

#define N_NODES 50000
#define E_EDGES 800000
#define IN_DIM  128
#define OUT_DIM 40
#define NPAD    50176
#define NBKT    196        // coarse buckets of 256 rows
#define NBLK    256        // blocks in coarse passes
#define EPB     3125       // edges per coarse block (256*3125 = 800000)

// workspace word offsets
#define OFF_CNT   0                         // 196*256
#define OFF_BASE  50176                     // 50176 (scan of cnt)
#define OFF_DEG   100352                    // 50176
#define OFF_RS    150528                    // 50176
#define OFF_EPACK 200704                    // 800000
#define OFF_SCOL  1000704                   // 800000
#define OFF_WTBF  1800704                   // 288*128 bf16 = 18432 words
#define OFF_WF2T  1819136                   // 48*288 bf16 = 6912 words
#define OFF_BV    1826048                   // 288 f32
#define OFF_XBF   1826336                   // NPAD*64
#define OFF_AXBF  (OFF_XBF  + NPAD * 64)
#define OFF_AAXBF (OFF_AXBF + NPAD * 64)
#define OFF_BTOT  (OFF_AAXBF + NPAD * 64)   // 256 (unused, kept for layout)
#define OFF_BOFF  (OFF_BTOT + 256)          // 256 (unused)

typedef short bf16x8 __attribute__((ext_vector_type(8)));
typedef float f32x4  __attribute__((ext_vector_type(4)));

__device__ __forceinline__ short f2bf(float f) {
    unsigned u = __float_as_uint(f);
    unsigned r = u + 0x7FFFu + ((u >> 16) & 1u);   // RNE
    return (short)(r >> 16);
}

__device__ __forceinline__ bf16x8 cvt8(float4 a, float4 b) {
    bf16x8 v;
    v[0] = f2bf(a.x); v[1] = f2bf(a.y); v[2] = f2bf(a.z); v[3] = f2bf(a.w);
    v[4] = f2bf(b.x); v[5] = f2bf(b.y); v[6] = f2bf(b.z); v[7] = f2bf(b.w);
    return v;
}

// 256-entry exclusive scan within a 256-thread block
__device__ __forceinline__ int block_excl_scan_256(int v, int* total_out,
                                                   int* wtot /*LDS[5]*/)
{
    const int t = threadIdx.x;
    const int lane = t & 63, wid = t >> 6;
    int sc = v;
    #pragma unroll
    for (int off = 1; off < 64; off <<= 1) {
        int tmp = __shfl_up(sc, off, 64);
        if (lane >= off) sc += tmp;
    }
    if (lane == 63) wtot[wid] = sc;
    __syncthreads();
    if (t == 0) {
        int a = 0;
        #pragma unroll
        for (int w2 = 0; w2 < 4; ++w2) { int tmp = wtot[w2]; wtot[w2] = a; a += tmp; }
        wtot[4] = a;
    }
    __syncthreads();
    *total_out = wtot[4];
    return sc - v + wtot[wid];
}

// -------- 1. prep: convert_x (blocks 0..3135) + coarse hist (3136..3391)
//             + weight repack (3392..3591) — mutually independent ------------
__global__ __launch_bounds__(256) void prep_kernel(
    const float* __restrict__ x, short* __restrict__ xbf,
    const int* __restrict__ row, int* __restrict__ cnt,
    const float* __restrict__ W0, const float* __restrict__ b0,
    const float* __restrict__ W1, const float* __restrict__ b1,
    const float* __restrict__ W2, const float* __restrict__ b2,
    const float* __restrict__ Wf,
    short* __restrict__ Wtbf, short* __restrict__ Wf2t,
    float* __restrict__ biasv)
{
    __shared__ int lbin[NBKT];
    const int t = threadIdx.x;
    const int b = blockIdx.x;

    if (b < 3136) {
        // ---- convert x fp32 -> bf16 (padded rows zeroed) ----
        int idx = b * 256 + t;                    // < NPAD*16
        int node = idx >> 4;
        bf16x8 v;
        if (node < N_NODES) {
            const float4* rp = (const float4*)x + (size_t)idx * 2;
            v = cvt8(rp[0], rp[1]);
        } else {
            #pragma unroll
            for (int j = 0; j < 8; ++j) v[j] = 0;
        }
        *(bf16x8*)(xbf + (size_t)idx * 8) = v;
    } else if (b < 3136 + NBLK) {
        // ---- coarse histogram ----
        const int blk = b - 3136;
        if (t < NBKT) lbin[t] = 0;
        __syncthreads();
        const int e0 = blk * EPB;
        for (int i = t; i < EPB; i += 256)
            atomicAdd(&lbin[row[e0 + i] >> 8], 1);
        __syncthreads();
        if (t < NBKT) cnt[t * NBLK + blk] = lbin[t];
    } else {
        // ---- weight repack ----
        int idx = (b - 3392) * 256 + t;
        if (idx < 288 * 128) {
            int v = idx >> 7, k = idx & 127;
            int s = v / 96, local = v - 96 * s;
            float val = 0.0f;
            if (s == 0 && local < 85)      val = W0[k * 85 + local];
            else if (s == 1 && local < 85) val = W1[k * 85 + local];
            else if (s == 2 && local < 86) val = W2[k * 86 + local];
            Wtbf[idx] = f2bf(val);
        } else if (idx < 288 * 128 + 48 * 288) {
            int j2 = idx - 288 * 128;
            int c = j2 / 288, v = j2 - c * 288;
            int s = v / 96, local = v - 96 * s;
            float val = 0.0f;
            if (c < OUT_DIM && local < ((s == 2) ? 86 : 85))
                val = Wf[(s * 85 + local) * OUT_DIM + c];
            Wf2t[j2] = f2bf(val);
        } else if (idx < 288 * 128 + 48 * 288 + 288) {
            int v = idx - (288 * 128 + 48 * 288);
            int s = v / 96, local = v - 96 * s;
            float val = 0.0f;
            if (s == 0 && local < 85)      val = b0[local];
            else if (s == 1 && local < 85) val = b1[local];
            else if (s == 2 && local < 86) val = b2[local];
            biasv[v] = val;
        }
    }
}

// -------- 2. fused global scan: local scan + redundant prefix re-sum -------
// block b: scans cnt[b*256 .. +255]; global offset = sum of cnt[0 .. b*256)
// recomputed locally (max 200 KB of L2-hot reads) — no inter-block comms.
__global__ __launch_bounds__(256) void scan_fused_kernel(
    const int* __restrict__ cnt, int* __restrict__ base)
{
    __shared__ int wtot[5];
    __shared__ int wsum[4];
    const int b = blockIdx.x;
    const int t = threadIdx.x;
    const int lane = t & 63, wid = t >> 6;

    int v = cnt[b * NBLK + t];
    int total;
    int excl = block_excl_scan_256(v, &total, wtot);

    // redundant sum of all preceding buckets' counts
    int partial = 0;
    const int lim = b * NBLK;
    for (int i = t; i < lim; i += 256) partial += cnt[i];
    #pragma unroll
    for (int off = 32; off > 0; off >>= 1)
        partial += __shfl_down(partial, off, 64);
    if (lane == 0) wsum[wid] = partial;
    __syncthreads();
    int goff = wsum[0] + wsum[1] + wsum[2] + wsum[3];

    base[b * NBLK + t] = excl + goff;
}

// -------- 3. coarse scatter -------------------------------------------------
__global__ __launch_bounds__(256) void scatter_coarse_kernel(
    const int* __restrict__ row, const int* __restrict__ col,
    const int* __restrict__ base, unsigned int* __restrict__ epack)
{
    __shared__ int lcnt[NBKT];
    __shared__ int lbs[NBKT];
    const int t   = threadIdx.x;
    const int blk = blockIdx.x;
    if (t < NBKT) { lcnt[t] = 0; lbs[t] = base[t * NBLK + blk]; }
    __syncthreads();
    const int e0 = blk * EPB;
    for (int i = t; i < EPB; i += 256) {
        int r = row[e0 + i];
        int c = col[e0 + i];
        int cb = r >> 8;
        int loc = atomicAdd(&lcnt[cb], 1);
        epack[lbs[cb] + loc] = ((unsigned)(r & 255) << 16) | (unsigned)c;
    }
}

// -------- 4. fine sort within bucket ---------------------------------------
__global__ __launch_bounds__(256) void fine_sort_kernel(
    const unsigned int* __restrict__ epack,
    const int* __restrict__ base,
    int* __restrict__ sorted_col,
    int* __restrict__ deg, int* __restrict__ row_start)
{
    __shared__ int lhist[256];
    __shared__ int lbase[256];
    __shared__ int wtot[5];
    const int t  = threadIdx.x;
    const int cb = blockIdx.x;
    const int s  = base[cb * NBLK];
    const int e2 = (cb == NBKT - 1) ? E_EDGES : base[(cb + 1) * NBLK];

    lhist[t] = 0;
    __syncthreads();
    for (int i = s + t; i < e2; i += 256)
        atomicAdd(&lhist[epack[i] >> 16], 1);
    __syncthreads();

    int v = lhist[t];
    int total;
    int excl = block_excl_scan_256(v, &total, wtot);

    int node = cb * 256 + t;
    deg[node]       = v;
    row_start[node] = s + excl;
    lbase[t] = excl;
    __syncthreads();
    lhist[t] = 0;
    __syncthreads();

    for (int i = s + t; i < e2; i += 256) {
        unsigned p = epack[i];
        int rlo = p >> 16;
        int off = atomicAdd(&lhist[rlo], 1);
        sorted_col[s + lbase[rlo] + off] = (int)(p & 0xFFFFu);
    }
}

// -------- 5. gather SPMM bf16: 16 lanes/node, 8-deep gather pipeline -------
__global__ __launch_bounds__(256) void spmm_gather_kernel(
    const short* __restrict__ src,
    const int*   __restrict__ row_start,
    const int*   __restrict__ sorted_col,
    short*       __restrict__ dst)
{
    int node = (blockIdx.x * 256 + threadIdx.x) >> 4;
    int lane = threadIdx.x & 15;
    if (node >= N_NODES) return;
    int s = row_start[node];
    int e = row_start[node + 1];

    float acc[8];
    #pragma unroll
    for (int j = 0; j < 8; ++j) acc[j] = 0.0f;

    for (int i = s; i < e; i += 8) {
        const int nn = e - i;
        int cidx[8];
        #pragma unroll
        for (int j = 0; j < 8; ++j)
            cidx[j] = sorted_col[i + (j < nn ? j : 0)];
        uint4 v[8];
        #pragma unroll
        for (int j = 0; j < 8; ++j)
            v[j] = *(const uint4*)(src + (size_t)cidx[j] * IN_DIM + lane * 8);
        #pragma unroll
        for (int j = 0; j < 8; ++j) {
            if (j < nn) {
                acc[0] += __uint_as_float(v[j].x << 16);
                acc[1] += __uint_as_float(v[j].x & 0xFFFF0000u);
                acc[2] += __uint_as_float(v[j].y << 16);
                acc[3] += __uint_as_float(v[j].y & 0xFFFF0000u);
                acc[4] += __uint_as_float(v[j].z << 16);
                acc[5] += __uint_as_float(v[j].z & 0xFFFF0000u);
                acc[6] += __uint_as_float(v[j].w << 16);
                acc[7] += __uint_as_float(v[j].w & 0xFFFF0000u);
            }
        }
    }
    bf16x8 r;
    #pragma unroll
    for (int j = 0; j < 8; ++j) r[j] = f2bf(acc[j]);
    *(bf16x8*)(dst + (size_t)node * IN_DIM + lane * 8) = r;
}

// -------- 6. fused dense, barrier-free: A prefetched, B from L2, h per-wave
// Each wave owns 16 rows; htile is per-wave private LDS (no __syncthreads).
// Layer-1 B-frags read from global Wtbf (36.9 KB, L2-replicated-hot).
// LDS = 37.9 KB -> 4 blocks/CU (vs 2 before); single A-latency exposure.
#define HTS 296     // h-tile row stride in shorts (592 B, 16B-aligned)

__global__ __launch_bounds__(256) void dense_fused_kernel(
    const short* __restrict__ xbf,
    const short* __restrict__ axbf,
    const short* __restrict__ aaxbf,
    const int*   __restrict__ deg,
    const short* __restrict__ Wtbf,
    const short* __restrict__ Wf2t,
    const float* __restrict__ biasv,
    const float* __restrict__ bfin,
    float* __restrict__ out)
{
    __shared__ short htile[4 * 16 * HTS];    // 37.9 KB, per-wave 16-row slabs

    const int tid  = threadIdx.x;
    const int w    = tid >> 6;
    const int lane = tid & 63;
    const int il   = lane & 15;
    const int kq   = lane >> 4;
    const int m0   = blockIdx.x * 64 + w * 16;
    const int arow = m0 + il;

    short* __restrict__ ht = htile + w * 16 * HTS;

    // prefetch ALL A fragments (12 x 16B/lane) + deg scales up front
    bf16x8 afr[3][4];
    #pragma unroll
    for (int kk = 0; kk < 4; ++kk) {
        afr[0][kk] = *(const bf16x8*)(xbf   + (size_t)arow * IN_DIM + kk * 32 + kq * 8);
        afr[1][kk] = *(const bf16x8*)(axbf  + (size_t)arow * IN_DIM + kk * 32 + kq * 8);
        afr[2][kk] = *(const bf16x8*)(aaxbf + (size_t)arow * IN_DIM + kk * 32 + kq * 8);
    }
    float dvj[4];
    #pragma unroll
    for (int j = 0; j < 4; ++j) {
        int node = m0 + kq * 4 + j;
        dvj[j] = 1.0f / fmaxf((float)deg[node], 1.0f);
    }

    #pragma unroll
    for (int s = 0; s < 3; ++s) {
        f32x4 acc[6];
        #pragma unroll
        for (int c = 0; c < 6; ++c)
            #pragma unroll
            for (int q = 0; q < 4; ++q) acc[c][q] = 0.0f;

        #pragma unroll
        for (int kk = 0; kk < 4; ++kk) {
            #pragma unroll
            for (int c = 0; c < 6; ++c) {
                bf16x8 bfrag = *(const bf16x8*)(
                    Wtbf + (size_t)(s * 96 + c * 16 + il) * IN_DIM + kk * 32 + kq * 8);
                acc[c] = __builtin_amdgcn_mfma_f32_16x16x32_bf16(
                    afr[s][kk], bfrag, acc[c], 0, 0, 0);
            }
        }

        #pragma unroll
        for (int j = 0; j < 4; ++j) {
            int nl = kq * 4 + j;                   // row within wave slab
            float sc = (s == 0) ? 1.0f : (s == 1) ? dvj[j] : dvj[j] * dvj[j];
            #pragma unroll
            for (int c = 0; c < 6; ++c) {
                int vcol = s * 96 + c * 16 + il;
                float hv = fmaf(acc[c][j], sc, biasv[vcol]);
                ht[nl * HTS + vcol] = f2bf(fmaxf(hv, 0.0f));
            }
        }
    }
    // no barrier: each wave reads only its own 16-row slab (lgkmcnt ordering)

    f32x4 acc2[3];
    #pragma unroll
    for (int cc = 0; cc < 3; ++cc)
        #pragma unroll
        for (int q = 0; q < 4; ++q) acc2[cc][q] = 0.0f;

    #pragma unroll
    for (int kk = 0; kk < 9; ++kk) {
        bf16x8 afrag = *(const bf16x8*)(ht + il * HTS + kk * 32 + kq * 8);
        #pragma unroll
        for (int cc = 0; cc < 3; ++cc) {
            bf16x8 bfrag = *(const bf16x8*)(
                Wf2t + (size_t)(cc * 16 + il) * 288 + kk * 32 + kq * 8);
            acc2[cc] = __builtin_amdgcn_mfma_f32_16x16x32_bf16(
                afrag, bfrag, acc2[cc], 0, 0, 0);
        }
    }

    #pragma unroll
    for (int cc = 0; cc < 3; ++cc) {
        int colo = cc * 16 + il;
        if (colo < OUT_DIM) {
            float b = bfin[colo];
            #pragma unroll
            for (int j = 0; j < 4; ++j) {
                int node = m0 + kq * 4 + j;
                if (node < N_NODES)
                    out[(size_t)node * OUT_DIM + colo] = acc2[cc][j] + b;
            }
        }
    }
}

extern "C" void kernel_launch(void* const* d_in, const int* in_sizes, int n_in,
                              void* d_out, int out_size, void* d_ws, size_t ws_size,
                              hipStream_t stream)
{
    const float* x  = (const float*)d_in[0];
    const int*   ei = (const int*)  d_in[1];
    const float* W0 = (const float*)d_in[2];
    const float* b0 = (const float*)d_in[3];
    const float* W1 = (const float*)d_in[4];
    const float* b1 = (const float*)d_in[5];
    const float* W2 = (const float*)d_in[6];
    const float* b2 = (const float*)d_in[7];
    const float* Wf = (const float*)d_in[8];
    const float* bf = (const float*)d_in[9];
    float* out = (float*)d_out;

    const int* row = ei;
    const int* col = ei + E_EDGES;

    int* wsw = (int*)d_ws;
    int*          cnt        = wsw + OFF_CNT;
    int*          base       = wsw + OFF_BASE;
    int*          deg        = wsw + OFF_DEG;
    int*          row_start  = wsw + OFF_RS;
    unsigned int* epack      = (unsigned int*)(wsw + OFF_EPACK);
    int*          sorted_col = wsw + OFF_SCOL;
    short*        Wtbf       = (short*)(wsw + OFF_WTBF);
    short*        Wf2t       = (short*)(wsw + OFF_WF2T);
    float*        biasv      = (float*)(wsw + OFF_BV);
    short*        xbf        = (short*)(wsw + OFF_XBF);
    short*        axbf       = (short*)(wsw + OFF_AXBF);
    short*        aaxbf      = (short*)(wsw + OFF_AAXBF);
    (void)ws_size; (void)in_sizes; (void)n_in; (void)out_size;

    dim3 blk(256);
    prep_kernel          <<<3136 + NBLK + 200, blk, 0, stream>>>(
        x, xbf, row, cnt, W0, b0, W1, b1, W2, b2, Wf, Wtbf, Wf2t, biasv);
    scan_fused_kernel    <<<NBKT, blk, 0, stream>>>(cnt, base);
    scatter_coarse_kernel<<<NBLK, blk, 0, stream>>>(row, col, base, epack);
    fine_sort_kernel     <<<NBKT, blk, 0, stream>>>(epack, base, sorted_col,
                                                    deg, row_start);

    const int sg = (N_NODES * 16 + 255) / 256;
    spmm_gather_kernel<<<sg, blk, 0, stream>>>(xbf,  row_start, sorted_col, axbf);
    spmm_gather_kernel<<<sg, blk, 0, stream>>>(axbf, row_start, sorted_col, aaxbf);

    dense_fused_kernel<<<NPAD / 64, blk, 0, stream>>>(
        xbf, axbf, aaxbf, deg, Wtbf, Wf2t, biasv, bf, out);
}

// Round 3
// 138.221 us; speedup vs baseline: 1.1757x; 1.1757x over previous
//
#include <hip/hip_runtime.h>

#define N_NODES 50000
#define E_EDGES 800000
#define IN_DIM  128
#define OUT_DIM 40
#define NPAD    50176
#define NBKT    196        // coarse buckets of 256 rows
#define NBLK    256        // blocks in coarse passes
#define EPB     3125       // edges per coarse block (256*3125 = 800000)

// workspace word offsets
#define OFF_CNT   0                         // 196*256
#define OFF_BASE  50176                     // 50176 (scan of cnt)
#define OFF_DEG   100352                    // 50176
#define OFF_RS    150528                    // 50176
#define OFF_EPACK 200704                    // 800000
#define OFF_SCOL  1000704                   // 800000
#define OFF_WTBF  1800704                   // 288*128 bf16 = 18432 words
#define OFF_WF2T  1819136                   // 48*288 bf16 = 6912 words
#define OFF_BV    1826048                   // 288 f32
#define OFF_XBF   1826336                   // NPAD*64
#define OFF_AXBF  (OFF_XBF  + NPAD * 64)
#define OFF_AAXBF (OFF_AXBF + NPAD * 64)
#define OFF_BTOT  (OFF_AAXBF + NPAD * 64)   // 256 (unused, kept for layout)
#define OFF_BOFF  (OFF_BTOT + 256)          // 256 (unused)

typedef short bf16x8 __attribute__((ext_vector_type(8)));
typedef float f32x4  __attribute__((ext_vector_type(4)));

__device__ __forceinline__ short f2bf(float f) {
    unsigned u = __float_as_uint(f);
    unsigned r = u + 0x7FFFu + ((u >> 16) & 1u);   // RNE
    return (short)(r >> 16);
}

__device__ __forceinline__ bf16x8 cvt8(float4 a, float4 b) {
    bf16x8 v;
    v[0] = f2bf(a.x); v[1] = f2bf(a.y); v[2] = f2bf(a.z); v[3] = f2bf(a.w);
    v[4] = f2bf(b.x); v[5] = f2bf(b.y); v[6] = f2bf(b.z); v[7] = f2bf(b.w);
    return v;
}

// 256-entry exclusive scan within a 256-thread block
__device__ __forceinline__ int block_excl_scan_256(int v, int* total_out,
                                                   int* wtot /*LDS[5]*/)
{
    const int t = threadIdx.x;
    const int lane = t & 63, wid = t >> 6;
    int sc = v;
    #pragma unroll
    for (int off = 1; off < 64; off <<= 1) {
        int tmp = __shfl_up(sc, off, 64);
        if (lane >= off) sc += tmp;
    }
    if (lane == 63) wtot[wid] = sc;
    __syncthreads();
    if (t == 0) {
        int a = 0;
        #pragma unroll
        for (int w2 = 0; w2 < 4; ++w2) { int tmp = wtot[w2]; wtot[w2] = a; a += tmp; }
        wtot[4] = a;
    }
    __syncthreads();
    *total_out = wtot[4];
    return sc - v + wtot[wid];
}

// -------- 1. prep: convert_x (blocks 0..3135) + coarse hist (3136..3391)
//             + weight repack (3392..3591) — mutually independent ------------
__global__ __launch_bounds__(256) void prep_kernel(
    const float* __restrict__ x, short* __restrict__ xbf,
    const int* __restrict__ row, int* __restrict__ cnt,
    const float* __restrict__ W0, const float* __restrict__ b0,
    const float* __restrict__ W1, const float* __restrict__ b1,
    const float* __restrict__ W2, const float* __restrict__ b2,
    const float* __restrict__ Wf,
    short* __restrict__ Wtbf, short* __restrict__ Wf2t,
    float* __restrict__ biasv)
{
    __shared__ int lbin[NBKT];
    const int t = threadIdx.x;
    const int b = blockIdx.x;

    if (b < 3136) {
        // ---- convert x fp32 -> bf16 (padded rows zeroed) ----
        int idx = b * 256 + t;                    // < NPAD*16
        int node = idx >> 4;
        bf16x8 v;
        if (node < N_NODES) {
            const float4* rp = (const float4*)x + (size_t)idx * 2;
            v = cvt8(rp[0], rp[1]);
        } else {
            #pragma unroll
            for (int j = 0; j < 8; ++j) v[j] = 0;
        }
        *(bf16x8*)(xbf + (size_t)idx * 8) = v;
    } else if (b < 3136 + NBLK) {
        // ---- coarse histogram ----
        const int blk = b - 3136;
        if (t < NBKT) lbin[t] = 0;
        __syncthreads();
        const int e0 = blk * EPB;
        for (int i = t; i < EPB; i += 256)
            atomicAdd(&lbin[row[e0 + i] >> 8], 1);
        __syncthreads();
        if (t < NBKT) cnt[t * NBLK + blk] = lbin[t];
    } else {
        // ---- weight repack ----
        int idx = (b - 3392) * 256 + t;
        if (idx < 288 * 128) {
            int v = idx >> 7, k = idx & 127;
            int s = v / 96, local = v - 96 * s;
            float val = 0.0f;
            if (s == 0 && local < 85)      val = W0[k * 85 + local];
            else if (s == 1 && local < 85) val = W1[k * 85 + local];
            else if (s == 2 && local < 86) val = W2[k * 86 + local];
            Wtbf[idx] = f2bf(val);
        } else if (idx < 288 * 128 + 48 * 288) {
            int j2 = idx - 288 * 128;
            int c = j2 / 288, v = j2 - c * 288;
            int s = v / 96, local = v - 96 * s;
            float val = 0.0f;
            if (c < OUT_DIM && local < ((s == 2) ? 86 : 85))
                val = Wf[(s * 85 + local) * OUT_DIM + c];
            Wf2t[j2] = f2bf(val);
        } else if (idx < 288 * 128 + 48 * 288 + 288) {
            int v = idx - (288 * 128 + 48 * 288);
            int s = v / 96, local = v - 96 * s;
            float val = 0.0f;
            if (s == 0 && local < 85)      val = b0[local];
            else if (s == 1 && local < 85) val = b1[local];
            else if (s == 2 && local < 86) val = b2[local];
            biasv[v] = val;
        }
    }
}

// -------- 2. fused global scan: local scan + redundant prefix re-sum -------
__global__ __launch_bounds__(256) void scan_fused_kernel(
    const int* __restrict__ cnt, int* __restrict__ base)
{
    __shared__ int wtot[5];
    __shared__ int wsum[4];
    const int b = blockIdx.x;
    const int t = threadIdx.x;
    const int lane = t & 63, wid = t >> 6;

    int v = cnt[b * NBLK + t];
    int total;
    int excl = block_excl_scan_256(v, &total, wtot);

    // redundant sum of all preceding buckets' counts
    int partial = 0;
    const int lim = b * NBLK;
    for (int i = t; i < lim; i += 256) partial += cnt[i];
    #pragma unroll
    for (int off = 32; off > 0; off >>= 1)
        partial += __shfl_down(partial, off, 64);
    if (lane == 0) wsum[wid] = partial;
    __syncthreads();
    int goff = wsum[0] + wsum[1] + wsum[2] + wsum[3];

    base[b * NBLK + t] = excl + goff;
}

// -------- 3. coarse scatter -------------------------------------------------
__global__ __launch_bounds__(256) void scatter_coarse_kernel(
    const int* __restrict__ row, const int* __restrict__ col,
    const int* __restrict__ base, unsigned int* __restrict__ epack)
{
    __shared__ int lcnt[NBKT];
    __shared__ int lbs[NBKT];
    const int t   = threadIdx.x;
    const int blk = blockIdx.x;
    if (t < NBKT) { lcnt[t] = 0; lbs[t] = base[t * NBLK + blk]; }
    __syncthreads();
    const int e0 = blk * EPB;
    for (int i = t; i < EPB; i += 256) {
        int r = row[e0 + i];
        int c = col[e0 + i];
        int cb = r >> 8;
        int loc = atomicAdd(&lcnt[cb], 1);
        epack[lbs[cb] + loc] = ((unsigned)(r & 255) << 16) | (unsigned)c;
    }
}

// -------- 4. fine sort within bucket ---------------------------------------
__global__ __launch_bounds__(256) void fine_sort_kernel(
    const unsigned int* __restrict__ epack,
    const int* __restrict__ base,
    int* __restrict__ sorted_col,
    int* __restrict__ deg, int* __restrict__ row_start)
{
    __shared__ int lhist[256];
    __shared__ int lbase[256];
    __shared__ int wtot[5];
    const int t  = threadIdx.x;
    const int cb = blockIdx.x;
    const int s  = base[cb * NBLK];
    const int e2 = (cb == NBKT - 1) ? E_EDGES : base[(cb + 1) * NBLK];

    lhist[t] = 0;
    __syncthreads();
    for (int i = s + t; i < e2; i += 256)
        atomicAdd(&lhist[epack[i] >> 16], 1);
    __syncthreads();

    int v = lhist[t];
    int total;
    int excl = block_excl_scan_256(v, &total, wtot);

    int node = cb * 256 + t;
    deg[node]       = v;
    row_start[node] = s + excl;
    lbase[t] = excl;
    __syncthreads();
    lhist[t] = 0;
    __syncthreads();

    for (int i = s + t; i < e2; i += 256) {
        unsigned p = epack[i];
        int rlo = p >> 16;
        int off = atomicAdd(&lhist[rlo], 1);
        sorted_col[s + lbase[rlo] + off] = (int)(p & 0xFFFFu);
    }
}

// -------- 5. gather SPMM bf16: 16 lanes/node, 8-deep gather pipeline -------
__global__ __launch_bounds__(256) void spmm_gather_kernel(
    const short* __restrict__ src,
    const int*   __restrict__ row_start,
    const int*   __restrict__ sorted_col,
    short*       __restrict__ dst)
{
    int node = (blockIdx.x * 256 + threadIdx.x) >> 4;
    int lane = threadIdx.x & 15;
    if (node >= N_NODES) return;
    int s = row_start[node];
    int e = row_start[node + 1];

    float acc[8];
    #pragma unroll
    for (int j = 0; j < 8; ++j) acc[j] = 0.0f;

    for (int i = s; i < e; i += 8) {
        const int nn = e - i;
        int cidx[8];
        #pragma unroll
        for (int j = 0; j < 8; ++j)
            cidx[j] = sorted_col[i + (j < nn ? j : 0)];
        uint4 v[8];
        #pragma unroll
        for (int j = 0; j < 8; ++j)
            v[j] = *(const uint4*)(src + (size_t)cidx[j] * IN_DIM + lane * 8);
        #pragma unroll
        for (int j = 0; j < 8; ++j) {
            if (j < nn) {
                acc[0] += __uint_as_float(v[j].x << 16);
                acc[1] += __uint_as_float(v[j].x & 0xFFFF0000u);
                acc[2] += __uint_as_float(v[j].y << 16);
                acc[3] += __uint_as_float(v[j].y & 0xFFFF0000u);
                acc[4] += __uint_as_float(v[j].z << 16);
                acc[5] += __uint_as_float(v[j].z & 0xFFFF0000u);
                acc[6] += __uint_as_float(v[j].w << 16);
                acc[7] += __uint_as_float(v[j].w & 0xFFFF0000u);
            }
        }
    }
    bf16x8 r;
    #pragma unroll
    for (int j = 0; j < 8; ++j) r[j] = f2bf(acc[j]);
    *(bf16x8*)(dst + (size_t)node * IN_DIM + lane * 8) = r;
}

// -------- 6. fused dense (PROVEN ~5 µs): W staged in LDS, h-tile in LDS ----
// block bx: rows bx*64 .. +63. Per s: stage W-slice in LDS (stride 132),
// MFMA 16x16x32, epilogue (scale/bias/relu) -> h-tile in LDS (stride 296).
// Then 288->48 MFMA with Wf2t streamed from global (L2-hot), biased store.
// NOTE (R1 post-mortem): do NOT replace wbuf staging with global B-frag
// loads — that puts ~200 cy L2 latency on every MFMA (51 µs, MfmaUtil 3%).
#define HTS 296     // h-tile row stride in shorts (592 B, 16B-aligned)

__global__ __launch_bounds__(256) void dense_fused_kernel(
    const short* __restrict__ xbf,
    const short* __restrict__ axbf,
    const short* __restrict__ aaxbf,
    const int*   __restrict__ deg,
    const short* __restrict__ Wtbf,
    const short* __restrict__ Wf2t,
    const float* __restrict__ biasv,
    const float* __restrict__ bfin,
    float* __restrict__ out)
{
    __shared__ short wbuf[96 * 132];     // 25.3 KB weight slice
    __shared__ short htile[64 * HTS];    // 37.9 KB h tile

    const int tid  = threadIdx.x;
    const int w    = tid >> 6;
    const int lane = tid & 63;
    const int il   = lane & 15;
    const int kq   = lane >> 4;
    const int m0   = blockIdx.x * 64 + w * 16;

    // per-lane deg scales for the 4 output rows this lane owns
    float dvj[4];
    #pragma unroll
    for (int j = 0; j < 4; ++j) {
        int node = m0 + kq * 4 + j;
        dvj[j] = 1.0f / fmaxf((float)deg[node], 1.0f);
    }

    #pragma unroll
    for (int s = 0; s < 3; ++s) {
        // stage Wtbf slice s: 96 rows x 16 slots of 16B = 1536 uint4
        #pragma unroll
        for (int j = 0; j < 6; ++j) {
            int idx  = tid + j * 256;
            int brow = idx >> 4;
            int slot = idx & 15;
            uint4 v = *(const uint4*)(Wtbf + (size_t)(s * 96 + brow) * IN_DIM + slot * 8);
            *(uint4*)(wbuf + brow * 132 + slot * 8) = v;
        }
        __syncthreads();

        const short* __restrict__ src = (s == 0) ? xbf : (s == 1) ? axbf : aaxbf;
        const int arow = m0 + il;

        f32x4 acc[6];
        #pragma unroll
        for (int c = 0; c < 6; ++c)
            #pragma unroll
            for (int q = 0; q < 4; ++q) acc[c][q] = 0.0f;

        #pragma unroll
        for (int kk = 0; kk < 4; ++kk) {
            bf16x8 afrag = *(const bf16x8*)(
                src + (size_t)arow * IN_DIM + kk * 32 + kq * 8);
            #pragma unroll
            for (int c = 0; c < 6; ++c) {
                bf16x8 bfrag = *(const bf16x8*)(
                    wbuf + (c * 16 + il) * 132 + kk * 32 + kq * 8);
                acc[c] = __builtin_amdgcn_mfma_f32_16x16x32_bf16(
                    afrag, bfrag, acc[c], 0, 0, 0);
            }
        }

        #pragma unroll
        for (int j = 0; j < 4; ++j) {
            int nl = w * 16 + kq * 4 + j;          // row within block
            float sc = (s == 0) ? 1.0f : (s == 1) ? dvj[j] : dvj[j] * dvj[j];
            #pragma unroll
            for (int c = 0; c < 6; ++c) {
                int vcol = s * 96 + c * 16 + il;
                float hv = fmaf(acc[c][j], sc, biasv[vcol]);
                htile[nl * HTS + vcol] = f2bf(fmaxf(hv, 0.0f));
            }
        }
        __syncthreads();   // wbuf reads done before restage; htile visible at end
    }

    // second layer: htile (LDS) x Wf2t (global, 27.6 KB, L2-hot)
    f32x4 acc2[3];
    #pragma unroll
    for (int cc = 0; cc < 3; ++cc)
        #pragma unroll
        for (int q = 0; q < 4; ++q) acc2[cc][q] = 0.0f;

    #pragma unroll
    for (int kk = 0; kk < 9; ++kk) {
        bf16x8 afrag = *(const bf16x8*)(
            htile + (w * 16 + il) * HTS + kk * 32 + kq * 8);
        #pragma unroll
        for (int cc = 0; cc < 3; ++cc) {
            bf16x8 bfrag = *(const bf16x8*)(
                Wf2t + (size_t)(cc * 16 + il) * 288 + kk * 32 + kq * 8);
            acc2[cc] = __builtin_amdgcn_mfma_f32_16x16x32_bf16(
                afrag, bfrag, acc2[cc], 0, 0, 0);
        }
    }

    #pragma unroll
    for (int cc = 0; cc < 3; ++cc) {
        int colo = cc * 16 + il;
        if (colo < OUT_DIM) {
            float b = bfin[colo];
            #pragma unroll
            for (int j = 0; j < 4; ++j) {
                int node = m0 + kq * 4 + j;
                if (node < N_NODES)
                    out[(size_t)node * OUT_DIM + colo] = acc2[cc][j] + b;
            }
        }
    }
}

extern "C" void kernel_launch(void* const* d_in, const int* in_sizes, int n_in,
                              void* d_out, int out_size, void* d_ws, size_t ws_size,
                              hipStream_t stream)
{
    const float* x  = (const float*)d_in[0];
    const int*   ei = (const int*)  d_in[1];
    const float* W0 = (const float*)d_in[2];
    const float* b0 = (const float*)d_in[3];
    const float* W1 = (const float*)d_in[4];
    const float* b1 = (const float*)d_in[5];
    const float* W2 = (const float*)d_in[6];
    const float* b2 = (const float*)d_in[7];
    const float* Wf = (const float*)d_in[8];
    const float* bf = (const float*)d_in[9];
    float* out = (float*)d_out;

    const int* row = ei;
    const int* col = ei + E_EDGES;

    int* wsw = (int*)d_ws;
    int*          cnt        = wsw + OFF_CNT;
    int*          base       = wsw + OFF_BASE;
    int*          deg        = wsw + OFF_DEG;
    int*          row_start  = wsw + OFF_RS;
    unsigned int* epack      = (unsigned int*)(wsw + OFF_EPACK);
    int*          sorted_col = wsw + OFF_SCOL;
    short*        Wtbf       = (short*)(wsw + OFF_WTBF);
    short*        Wf2t       = (short*)(wsw + OFF_WF2T);
    float*        biasv      = (float*)(wsw + OFF_BV);
    short*        xbf        = (short*)(wsw + OFF_XBF);
    short*        axbf       = (short*)(wsw + OFF_AXBF);
    short*        aaxbf      = (short*)(wsw + OFF_AAXBF);
    (void)ws_size; (void)in_sizes; (void)n_in; (void)out_size;

    dim3 blk(256);
    prep_kernel          <<<3136 + NBLK + 200, blk, 0, stream>>>(
        x, xbf, row, cnt, W0, b0, W1, b1, W2, b2, Wf, Wtbf, Wf2t, biasv);
    scan_fused_kernel    <<<NBKT, blk, 0, stream>>>(cnt, base);
    scatter_coarse_kernel<<<NBLK, blk, 0, stream>>>(row, col, base, epack);
    fine_sort_kernel     <<<NBKT, blk, 0, stream>>>(epack, base, sorted_col,
                                                    deg, row_start);

    const int sg = (N_NODES * 16 + 255) / 256;
    spmm_gather_kernel<<<sg, blk, 0, stream>>>(xbf,  row_start, sorted_col, axbf);
    spmm_gather_kernel<<<sg, blk, 0, stream>>>(axbf, row_start, sorted_col, aaxbf);

    dense_fused_kernel<<<NPAD / 64, blk, 0, stream>>>(
        xbf, axbf, aaxbf, deg, Wtbf, Wf2t, biasv, bf, out);
}

// Round 4
// 116.444 us; speedup vs baseline: 1.3956x; 1.1870x over previous
//
#include <hip/hip_runtime.h>

#define N_NODES 50000
#define E_EDGES 800000
#define IN_DIM  128
#define OUT_DIM 40
#define NPAD    50176
#define NBKT    196        // coarse buckets of 256 rows
#define NBLK    256        // blocks in coarse passes
#define EPB     3125       // edges per coarse block (256*3125 = 800000)

// workspace word offsets
#define OFF_CNT   0                         // 196*256
#define OFF_BASE  50176                     // 50176 (scan of cnt)
#define OFF_DEG   100352                    // 50176
#define OFF_RS    150528                    // 50176
#define OFF_EPACK 200704                    // 800000
#define OFF_SCOL  1000704                   // 800000
#define OFF_WTBF  1800704                   // 288*128 bf16 = 18432 words
#define OFF_WF2T  1819136                   // 48*288 bf16 = 6912 words
#define OFF_BV    1826048                   // 288 f32
#define OFF_XBF   1826336                   // NPAD*64
#define OFF_AXBF  (OFF_XBF  + NPAD * 64)
#define OFF_AAXBF (OFF_AXBF + NPAD * 64)
#define OFF_BTOT  (OFF_AAXBF + NPAD * 64)   // 256
#define OFF_BOFF  (OFF_BTOT + 256)          // 256

typedef short bf16x8 __attribute__((ext_vector_type(8)));
typedef float f32x4  __attribute__((ext_vector_type(4)));

__device__ __forceinline__ short f2bf(float f) {
    unsigned u = __float_as_uint(f);
    unsigned r = u + 0x7FFFu + ((u >> 16) & 1u);   // RNE
    return (short)(r >> 16);
}

__device__ __forceinline__ bf16x8 cvt8(float4 a, float4 b) {
    bf16x8 v;
    v[0] = f2bf(a.x); v[1] = f2bf(a.y); v[2] = f2bf(a.z); v[3] = f2bf(a.w);
    v[4] = f2bf(b.x); v[5] = f2bf(b.y); v[6] = f2bf(b.z); v[7] = f2bf(b.w);
    return v;
}

// 256-entry exclusive scan within a 256-thread block
__device__ __forceinline__ int block_excl_scan_256(int v, int* total_out,
                                                   int* wtot /*LDS[5]*/)
{
    const int t = threadIdx.x;
    const int lane = t & 63, wid = t >> 6;
    int sc = v;
    #pragma unroll
    for (int off = 1; off < 64; off <<= 1) {
        int tmp = __shfl_up(sc, off, 64);
        if (lane >= off) sc += tmp;
    }
    if (lane == 63) wtot[wid] = sc;
    __syncthreads();
    if (t == 0) {
        int a = 0;
        #pragma unroll
        for (int w2 = 0; w2 < 4; ++w2) { int tmp = wtot[w2]; wtot[w2] = a; a += tmp; }
        wtot[4] = a;
    }
    __syncthreads();
    *total_out = wtot[4];
    return sc - v + wtot[wid];
}

// -------- 1. prep: convert_x (blocks 0..3135) + coarse hist (3136..3391)
//             + weight repack (3392..3591) — mutually independent ------------
__global__ __launch_bounds__(256) void prep_kernel(
    const float* __restrict__ x, short* __restrict__ xbf,
    const int* __restrict__ row, int* __restrict__ cnt,
    const float* __restrict__ W0, const float* __restrict__ b0,
    const float* __restrict__ W1, const float* __restrict__ b1,
    const float* __restrict__ W2, const float* __restrict__ b2,
    const float* __restrict__ Wf,
    short* __restrict__ Wtbf, short* __restrict__ Wf2t,
    float* __restrict__ biasv)
{
    __shared__ int lbin[NBKT];
    const int t = threadIdx.x;
    const int b = blockIdx.x;

    if (b < 3136) {
        // ---- convert x fp32 -> bf16 (padded rows zeroed) ----
        int idx = b * 256 + t;                    // < NPAD*16
        int node = idx >> 4;
        bf16x8 v;
        if (node < N_NODES) {
            const float4* rp = (const float4*)x + (size_t)idx * 2;
            v = cvt8(rp[0], rp[1]);
        } else {
            #pragma unroll
            for (int j = 0; j < 8; ++j) v[j] = 0;
        }
        *(bf16x8*)(xbf + (size_t)idx * 8) = v;
    } else if (b < 3136 + NBLK) {
        // ---- coarse histogram ----
        const int blk = b - 3136;
        if (t < NBKT) lbin[t] = 0;
        __syncthreads();
        const int e0 = blk * EPB;
        for (int i = t; i < EPB; i += 256)
            atomicAdd(&lbin[row[e0 + i] >> 8], 1);
        __syncthreads();
        if (t < NBKT) cnt[t * NBLK + blk] = lbin[t];
    } else {
        // ---- weight repack ----
        int idx = (b - 3392) * 256 + t;
        if (idx < 288 * 128) {
            int v = idx >> 7, k = idx & 127;
            int s = v / 96, local = v - 96 * s;
            float val = 0.0f;
            if (s == 0 && local < 85)      val = W0[k * 85 + local];
            else if (s == 1 && local < 85) val = W1[k * 85 + local];
            else if (s == 2 && local < 86) val = W2[k * 86 + local];
            Wtbf[idx] = f2bf(val);
        } else if (idx < 288 * 128 + 48 * 288) {
            int j2 = idx - 288 * 128;
            int c = j2 / 288, v = j2 - c * 288;
            int s = v / 96, local = v - 96 * s;
            float val = 0.0f;
            if (c < OUT_DIM && local < ((s == 2) ? 86 : 85))
                val = Wf[(s * 85 + local) * OUT_DIM + c];
            Wf2t[j2] = f2bf(val);
        } else if (idx < 288 * 128 + 48 * 288 + 288) {
            int v = idx - (288 * 128 + 48 * 288);
            int s = v / 96, local = v - 96 * s;
            float val = 0.0f;
            if (s == 0 && local < 85)      val = b0[local];
            else if (s == 1 && local < 85) val = b1[local];
            else if (s == 2 && local < 86) val = b2[local];
            biasv[v] = val;
        }
    }
}

// -------- 2a. per-bin local scan -------------------------------------------
__global__ __launch_bounds__(256) void scan_local_kernel(
    const int* __restrict__ cnt, int* __restrict__ base,
    int* __restrict__ btot)
{
    __shared__ int wtot[5];
    const int b = blockIdx.x;
    const int t = threadIdx.x;
    int v = cnt[b * NBLK + t];
    int total;
    int excl = block_excl_scan_256(v, &total, wtot);
    base[b * NBLK + t] = excl;
    if (t == 0) btot[b] = total;
}

// -------- 2b. scan bin totals + add offsets (merged) -----------------------
// each of 196 blocks redundantly scans the 196 totals, then adds its offset
__global__ __launch_bounds__(256) void scan_add_kernel(
    const int* __restrict__ btot, int* __restrict__ base)
{
    __shared__ int wtot[5];
    __shared__ int sh[256];
    const int t = threadIdx.x;
    const int b = blockIdx.x;
    int v = (t < NBKT) ? btot[t] : 0;
    int total;
    int excl = block_excl_scan_256(v, &total, wtot);
    sh[t] = excl;
    __syncthreads();
    int off = sh[b];
    base[b * NBLK + t] += off;
}

// -------- 3. coarse scatter -------------------------------------------------
__global__ __launch_bounds__(256) void scatter_coarse_kernel(
    const int* __restrict__ row, const int* __restrict__ col,
    const int* __restrict__ base, unsigned int* __restrict__ epack)
{
    __shared__ int lcnt[NBKT];
    __shared__ int lbs[NBKT];
    const int t   = threadIdx.x;
    const int blk = blockIdx.x;
    if (t < NBKT) { lcnt[t] = 0; lbs[t] = base[t * NBLK + blk]; }
    __syncthreads();
    const int e0 = blk * EPB;
    for (int i = t; i < EPB; i += 256) {
        int r = row[e0 + i];
        int c = col[e0 + i];
        int cb = r >> 8;
        int loc = atomicAdd(&lcnt[cb], 1);
        epack[lbs[cb] + loc] = ((unsigned)(r & 255) << 16) | (unsigned)c;
    }
}

// -------- 4. fine sort within bucket ---------------------------------------
__global__ __launch_bounds__(256) void fine_sort_kernel(
    const unsigned int* __restrict__ epack,
    const int* __restrict__ base,
    int* __restrict__ sorted_col,
    int* __restrict__ deg, int* __restrict__ row_start)
{
    __shared__ int lhist[256];
    __shared__ int lbase[256];
    __shared__ int wtot[5];
    const int t  = threadIdx.x;
    const int cb = blockIdx.x;
    const int s  = base[cb * NBLK];
    const int e2 = (cb == NBKT - 1) ? E_EDGES : base[(cb + 1) * NBLK];

    lhist[t] = 0;
    __syncthreads();
    for (int i = s + t; i < e2; i += 256)
        atomicAdd(&lhist[epack[i] >> 16], 1);
    __syncthreads();

    int v = lhist[t];
    int total;
    int excl = block_excl_scan_256(v, &total, wtot);

    int node = cb * 256 + t;
    deg[node]       = v;
    row_start[node] = s + excl;
    lbase[t] = excl;
    __syncthreads();
    lhist[t] = 0;
    __syncthreads();

    for (int i = s + t; i < e2; i += 256) {
        unsigned p = epack[i];
        int rlo = p >> 16;
        int off = atomicAdd(&lhist[rlo], 1);
        sorted_col[s + lbase[rlo] + off] = (int)(p & 0xFFFFu);
    }
}

// -------- 5. gather SPMM bf16: 16 lanes/node, 8-deep gather pipeline -------
__global__ __launch_bounds__(256) void spmm_gather_kernel(
    const short* __restrict__ src,
    const int*   __restrict__ row_start,
    const int*   __restrict__ sorted_col,
    short*       __restrict__ dst)
{
    int node = (blockIdx.x * 256 + threadIdx.x) >> 4;
    int lane = threadIdx.x & 15;
    if (node >= N_NODES) return;
    int s = row_start[node];
    int e = row_start[node + 1];

    float acc[8];
    #pragma unroll
    for (int j = 0; j < 8; ++j) acc[j] = 0.0f;

    for (int i = s; i < e; i += 8) {
        const int nn = e - i;
        int cidx[8];
        #pragma unroll
        for (int j = 0; j < 8; ++j)
            cidx[j] = sorted_col[i + (j < nn ? j : 0)];
        uint4 v[8];
        #pragma unroll
        for (int j = 0; j < 8; ++j)
            v[j] = *(const uint4*)(src + (size_t)cidx[j] * IN_DIM + lane * 8);
        #pragma unroll
        for (int j = 0; j < 8; ++j) {
            if (j < nn) {
                acc[0] += __uint_as_float(v[j].x << 16);
                acc[1] += __uint_as_float(v[j].x & 0xFFFF0000u);
                acc[2] += __uint_as_float(v[j].y << 16);
                acc[3] += __uint_as_float(v[j].y & 0xFFFF0000u);
                acc[4] += __uint_as_float(v[j].z << 16);
                acc[5] += __uint_as_float(v[j].z & 0xFFFF0000u);
                acc[6] += __uint_as_float(v[j].w << 16);
                acc[7] += __uint_as_float(v[j].w & 0xFFFF0000u);
            }
        }
    }
    bf16x8 r;
    #pragma unroll
    for (int j = 0; j < 8; ++j) r[j] = f2bf(acc[j]);
    *(bf16x8*)(dst + (size_t)node * IN_DIM + lane * 8) = r;
}

// -------- 6. fused dense: (x|ax|aax) @ Wt -> relu h (LDS) -> @ Wf -> out ---
// block bx: rows bx*64 .. +63. Per s: stage W-slice in LDS (stride 132),
// MFMA 16x16x32, epilogue (scale/bias/relu) -> h-tile in LDS (stride 296).
// Then 288->48 MFMA with Wf2t streamed from global (L2-hot), biased store.
// NOTE (R1 post-mortem): do NOT replace wbuf staging with global B-frag
// loads — that puts ~200 cy L2 latency on every MFMA (51 µs, MfmaUtil 3%).
#define HTS 296     // h-tile row stride in shorts (592 B, 16B-aligned)

__global__ __launch_bounds__(256) void dense_fused_kernel(
    const short* __restrict__ xbf,
    const short* __restrict__ axbf,
    const short* __restrict__ aaxbf,
    const int*   __restrict__ deg,
    const short* __restrict__ Wtbf,
    const short* __restrict__ Wf2t,
    const float* __restrict__ biasv,
    const float* __restrict__ bfin,
    float* __restrict__ out)
{
    __shared__ short wbuf[96 * 132];     // 25.3 KB weight slice
    __shared__ short htile[64 * HTS];    // 37.9 KB h tile

    const int tid  = threadIdx.x;
    const int w    = tid >> 6;
    const int lane = tid & 63;
    const int il   = lane & 15;
    const int kq   = lane >> 4;
    const int m0   = blockIdx.x * 64 + w * 16;

    // per-lane deg scales for the 4 output rows this lane owns
    float dvj[4];
    #pragma unroll
    for (int j = 0; j < 4; ++j) {
        int node = m0 + kq * 4 + j;
        dvj[j] = 1.0f / fmaxf((float)deg[node], 1.0f);
    }

    #pragma unroll
    for (int s = 0; s < 3; ++s) {
        // stage Wtbf slice s: 96 rows x 16 slots of 16B = 1536 uint4
        #pragma unroll
        for (int j = 0; j < 6; ++j) {
            int idx  = tid + j * 256;
            int brow = idx >> 4;
            int slot = idx & 15;
            uint4 v = *(const uint4*)(Wtbf + (size_t)(s * 96 + brow) * IN_DIM + slot * 8);
            *(uint4*)(wbuf + brow * 132 + slot * 8) = v;
        }
        __syncthreads();

        const short* __restrict__ src = (s == 0) ? xbf : (s == 1) ? axbf : aaxbf;
        const int arow = m0 + il;

        f32x4 acc[6];
        #pragma unroll
        for (int c = 0; c < 6; ++c)
            #pragma unroll
            for (int q = 0; q < 4; ++q) acc[c][q] = 0.0f;

        #pragma unroll
        for (int kk = 0; kk < 4; ++kk) {
            bf16x8 afrag = *(const bf16x8*)(
                src + (size_t)arow * IN_DIM + kk * 32 + kq * 8);
            #pragma unroll
            for (int c = 0; c < 6; ++c) {
                bf16x8 bfrag = *(const bf16x8*)(
                    wbuf + (c * 16 + il) * 132 + kk * 32 + kq * 8);
                acc[c] = __builtin_amdgcn_mfma_f32_16x16x32_bf16(
                    afrag, bfrag, acc[c], 0, 0, 0);
            }
        }

        #pragma unroll
        for (int j = 0; j < 4; ++j) {
            int nl = w * 16 + kq * 4 + j;          // row within block
            float sc = (s == 0) ? 1.0f : (s == 1) ? dvj[j] : dvj[j] * dvj[j];
            #pragma unroll
            for (int c = 0; c < 6; ++c) {
                int vcol = s * 96 + c * 16 + il;
                float hv = fmaf(acc[c][j], sc, biasv[vcol]);
                htile[nl * HTS + vcol] = f2bf(fmaxf(hv, 0.0f));
            }
        }
        __syncthreads();   // wbuf reads done before restage; htile visible at end
    }

    // second layer: htile (LDS) x Wf2t (global, 27.6 KB, L2-hot)
    f32x4 acc2[3];
    #pragma unroll
    for (int cc = 0; cc < 3; ++cc)
        #pragma unroll
        for (int q = 0; q < 4; ++q) acc2[cc][q] = 0.0f;

    #pragma unroll
    for (int kk = 0; kk < 9; ++kk) {
        bf16x8 afrag = *(const bf16x8*)(
            htile + (w * 16 + il) * HTS + kk * 32 + kq * 8);
        #pragma unroll
        for (int cc = 0; cc < 3; ++cc) {
            bf16x8 bfrag = *(const bf16x8*)(
                Wf2t + (size_t)(cc * 16 + il) * 288 + kk * 32 + kq * 8);
            acc2[cc] = __builtin_amdgcn_mfma_f32_16x16x32_bf16(
                afrag, bfrag, acc2[cc], 0, 0, 0);
        }
    }

    #pragma unroll
    for (int cc = 0; cc < 3; ++cc) {
        int colo = cc * 16 + il;
        if (colo < OUT_DIM) {
            float b = bfin[colo];
            #pragma unroll
            for (int j = 0; j < 4; ++j) {
                int node = m0 + kq * 4 + j;
                if (node < N_NODES)
                    out[(size_t)node * OUT_DIM + colo] = acc2[cc][j] + b;
            }
        }
    }
}

extern "C" void kernel_launch(void* const* d_in, const int* in_sizes, int n_in,
                              void* d_out, int out_size, void* d_ws, size_t ws_size,
                              hipStream_t stream)
{
    const float* x  = (const float*)d_in[0];
    const int*   ei = (const int*)  d_in[1];
    const float* W0 = (const float*)d_in[2];
    const float* b0 = (const float*)d_in[3];
    const float* W1 = (const float*)d_in[4];
    const float* b1 = (const float*)d_in[5];
    const float* W2 = (const float*)d_in[6];
    const float* b2 = (const float*)d_in[7];
    const float* Wf = (const float*)d_in[8];
    const float* bf = (const float*)d_in[9];
    float* out = (float*)d_out;

    const int* row = ei;
    const int* col = ei + E_EDGES;

    int* wsw = (int*)d_ws;
    int*          cnt        = wsw + OFF_CNT;
    int*          base       = wsw + OFF_BASE;
    int*          deg        = wsw + OFF_DEG;
    int*          row_start  = wsw + OFF_RS;
    unsigned int* epack      = (unsigned int*)(wsw + OFF_EPACK);
    int*          sorted_col = wsw + OFF_SCOL;
    short*        Wtbf       = (short*)(wsw + OFF_WTBF);
    short*        Wf2t       = (short*)(wsw + OFF_WF2T);
    float*        biasv      = (float*)(wsw + OFF_BV);
    short*        xbf        = (short*)(wsw + OFF_XBF);
    short*        axbf       = (short*)(wsw + OFF_AXBF);
    short*        aaxbf      = (short*)(wsw + OFF_AAXBF);
    int*          btot       = wsw + OFF_BTOT;
    int*          boff       = wsw + OFF_BOFF;
    (void)boff; (void)ws_size; (void)in_sizes; (void)n_in; (void)out_size;

    dim3 blk(256);
    prep_kernel          <<<3136 + NBLK + 200, blk, 0, stream>>>(
        x, xbf, row, cnt, W0, b0, W1, b1, W2, b2, Wf, Wtbf, Wf2t, biasv);
    scan_local_kernel    <<<NBKT, blk, 0, stream>>>(cnt, base, btot);
    scan_add_kernel      <<<NBKT, blk, 0, stream>>>(btot, base);
    scatter_coarse_kernel<<<NBLK, blk, 0, stream>>>(row, col, base, epack);
    fine_sort_kernel     <<<NBKT, blk, 0, stream>>>(epack, base, sorted_col,
                                                    deg, row_start);

    const int sg = (N_NODES * 16 + 255) / 256;
    spmm_gather_kernel<<<sg, blk, 0, stream>>>(xbf,  row_start, sorted_col, axbf);
    spmm_gather_kernel<<<sg, blk, 0, stream>>>(axbf, row_start, sorted_col, aaxbf);

    dense_fused_kernel<<<NPAD / 64, blk, 0, stream>>>(
        xbf, axbf, aaxbf, deg, Wtbf, Wf2t, biasv, bf, out);
}

// Round 5
// 116.092 us; speedup vs baseline: 1.3998x; 1.0030x over previous
//
#include <hip/hip_runtime.h>

#define N_NODES 50000
#define E_EDGES 800000
#define IN_DIM  128
#define OUT_DIM 40
#define NPAD    50176
#define NBKT    196        // coarse buckets of 256 rows
#define NBLK    256        // blocks in coarse passes
#define EPB     3125       // edges per coarse block (256*3125 = 800000)

// workspace word offsets
#define OFF_CNT   0                         // 196*256
#define OFF_BASE  50176                     // 50176 (scan of cnt)
#define OFF_DEG   100352                    // 50176
#define OFF_RS    150528                    // 50176
#define OFF_EPACK 200704                    // 800000
#define OFF_SCOL  1000704                   // 800000
#define OFF_WTBF  1800704                   // 288*128 bf16 = 18432 words
#define OFF_WF2T  1819136                   // 48*288 bf16 = 6912 words
#define OFF_BV    1826048                   // 288 f32
#define OFF_XBF   1826336                   // NPAD*64
#define OFF_AXBF  (OFF_XBF  + NPAD * 64)
#define OFF_AAXBF (OFF_AXBF + NPAD * 64)
#define OFF_BTOT  (OFF_AAXBF + NPAD * 64)   // 256
#define OFF_BOFF  (OFF_BTOT + 256)          // 256

typedef short bf16x8 __attribute__((ext_vector_type(8)));
typedef float f32x4  __attribute__((ext_vector_type(4)));

__device__ __forceinline__ short f2bf(float f) {
    unsigned u = __float_as_uint(f);
    unsigned r = u + 0x7FFFu + ((u >> 16) & 1u);   // RNE
    return (short)(r >> 16);
}

__device__ __forceinline__ bf16x8 cvt8(float4 a, float4 b) {
    bf16x8 v;
    v[0] = f2bf(a.x); v[1] = f2bf(a.y); v[2] = f2bf(a.z); v[3] = f2bf(a.w);
    v[4] = f2bf(b.x); v[5] = f2bf(b.y); v[6] = f2bf(b.z); v[7] = f2bf(b.w);
    return v;
}

// 256-entry exclusive scan within a 256-thread block
__device__ __forceinline__ int block_excl_scan_256(int v, int* total_out,
                                                   int* wtot /*LDS[5]*/)
{
    const int t = threadIdx.x;
    const int lane = t & 63, wid = t >> 6;
    int sc = v;
    #pragma unroll
    for (int off = 1; off < 64; off <<= 1) {
        int tmp = __shfl_up(sc, off, 64);
        if (lane >= off) sc += tmp;
    }
    if (lane == 63) wtot[wid] = sc;
    __syncthreads();
    if (t == 0) {
        int a = 0;
        #pragma unroll
        for (int w2 = 0; w2 < 4; ++w2) { int tmp = wtot[w2]; wtot[w2] = a; a += tmp; }
        wtot[4] = a;
    }
    __syncthreads();
    *total_out = wtot[4];
    return sc - v + wtot[wid];
}

// -------- 1. prep: convert_x (blocks 0..3135) + coarse hist (3136..3391)
//             + weight repack (3392..3591) — mutually independent ------------
__global__ __launch_bounds__(256) void prep_kernel(
    const float* __restrict__ x, short* __restrict__ xbf,
    const int* __restrict__ row, int* __restrict__ cnt,
    const float* __restrict__ W0, const float* __restrict__ b0,
    const float* __restrict__ W1, const float* __restrict__ b1,
    const float* __restrict__ W2, const float* __restrict__ b2,
    const float* __restrict__ Wf,
    short* __restrict__ Wtbf, short* __restrict__ Wf2t,
    float* __restrict__ biasv)
{
    __shared__ int lbin[NBKT];
    const int t = threadIdx.x;
    const int b = blockIdx.x;

    if (b < 3136) {
        // ---- convert x fp32 -> bf16 (padded rows zeroed) ----
        int idx = b * 256 + t;                    // < NPAD*16
        int node = idx >> 4;
        bf16x8 v;
        if (node < N_NODES) {
            const float4* rp = (const float4*)x + (size_t)idx * 2;
            v = cvt8(rp[0], rp[1]);
        } else {
            #pragma unroll
            for (int j = 0; j < 8; ++j) v[j] = 0;
        }
        *(bf16x8*)(xbf + (size_t)idx * 8) = v;
    } else if (b < 3136 + NBLK) {
        // ---- coarse histogram ----
        const int blk = b - 3136;
        if (t < NBKT) lbin[t] = 0;
        __syncthreads();
        const int e0 = blk * EPB;
        for (int i = t; i < EPB; i += 256)
            atomicAdd(&lbin[row[e0 + i] >> 8], 1);
        __syncthreads();
        if (t < NBKT) cnt[t * NBLK + blk] = lbin[t];
    } else {
        // ---- weight repack ----
        int idx = (b - 3392) * 256 + t;
        if (idx < 288 * 128) {
            int v = idx >> 7, k = idx & 127;
            int s = v / 96, local = v - 96 * s;
            float val = 0.0f;
            if (s == 0 && local < 85)      val = W0[k * 85 + local];
            else if (s == 1 && local < 85) val = W1[k * 85 + local];
            else if (s == 2 && local < 86) val = W2[k * 86 + local];
            Wtbf[idx] = f2bf(val);
        } else if (idx < 288 * 128 + 48 * 288) {
            int j2 = idx - 288 * 128;
            int c = j2 / 288, v = j2 - c * 288;
            int s = v / 96, local = v - 96 * s;
            float val = 0.0f;
            if (c < OUT_DIM && local < ((s == 2) ? 86 : 85))
                val = Wf[(s * 85 + local) * OUT_DIM + c];
            Wf2t[j2] = f2bf(val);
        } else if (idx < 288 * 128 + 48 * 288 + 288) {
            int v = idx - (288 * 128 + 48 * 288);
            int s = v / 96, local = v - 96 * s;
            float val = 0.0f;
            if (s == 0 && local < 85)      val = b0[local];
            else if (s == 1 && local < 85) val = b1[local];
            else if (s == 2 && local < 86) val = b2[local];
            biasv[v] = val;
        }
    }
}

// -------- 2a. per-bin local scan -------------------------------------------
__global__ __launch_bounds__(256) void scan_local_kernel(
    const int* __restrict__ cnt, int* __restrict__ base,
    int* __restrict__ btot)
{
    __shared__ int wtot[5];
    const int b = blockIdx.x;
    const int t = threadIdx.x;
    int v = cnt[b * NBLK + t];
    int total;
    int excl = block_excl_scan_256(v, &total, wtot);
    base[b * NBLK + t] = excl;
    if (t == 0) btot[b] = total;
}

// -------- 2b. scan bin totals + add offsets (merged) -----------------------
// each of 196 blocks redundantly scans the 196 totals, then adds its offset
// NOTE (R3/R4 A/B): do NOT fold the global prefix into a per-block redundant
// re-sum of cnt (scan_fused): 196 blocks x ~195 serialized L2 loads = +22 us.
__global__ __launch_bounds__(256) void scan_add_kernel(
    const int* __restrict__ btot, int* __restrict__ base)
{
    __shared__ int wtot[5];
    __shared__ int sh[256];
    const int t = threadIdx.x;
    const int b = blockIdx.x;
    int v = (t < NBKT) ? btot[t] : 0;
    int total;
    int excl = block_excl_scan_256(v, &total, wtot);
    sh[t] = excl;
    __syncthreads();
    int off = sh[b];
    base[b * NBLK + t] += off;
}

// -------- 3. coarse scatter -------------------------------------------------
__global__ __launch_bounds__(256) void scatter_coarse_kernel(
    const int* __restrict__ row, const int* __restrict__ col,
    const int* __restrict__ base, unsigned int* __restrict__ epack)
{
    __shared__ int lcnt[NBKT];
    __shared__ int lbs[NBKT];
    const int t   = threadIdx.x;
    const int blk = blockIdx.x;
    if (t < NBKT) { lcnt[t] = 0; lbs[t] = base[t * NBLK + blk]; }
    __syncthreads();
    const int e0 = blk * EPB;
    for (int i = t; i < EPB; i += 256) {
        int r = row[e0 + i];
        int c = col[e0 + i];
        int cb = r >> 8;
        int loc = atomicAdd(&lcnt[cb], 1);
        epack[lbs[cb] + loc] = ((unsigned)(r & 255) << 16) | (unsigned)c;
    }
}

// -------- 4. fine sort within bucket, col-range-major within row -----------
// 1024 bins: key = (rlo<<2) | (col>>14). Each row's neighbor list comes out
// grouped by 16K-row col ranges (4 MB = one XCD L2). All spmm blocks sweep
// ranges 0->3 in order, so the instantaneous gather working set per XCD is
// ~1 range instead of the whole 12.8 MB table -> higher L2 hit rate.
// Neighbor-order change only reorders f32 adds (safe: << bf16 quantum).
__global__ __launch_bounds__(256) void fine_sort_kernel(
    const unsigned int* __restrict__ epack,
    const int* __restrict__ base,
    int* __restrict__ sorted_col,
    int* __restrict__ deg, int* __restrict__ row_start)
{
    __shared__ int lhist[1024];
    __shared__ int lbase[1024];
    __shared__ int wtot[5];
    const int t  = threadIdx.x;
    const int cb = blockIdx.x;
    const int s  = base[cb * NBLK];
    const int e2 = (cb == NBKT - 1) ? E_EDGES : base[(cb + 1) * NBLK];

    #pragma unroll
    for (int j = 0; j < 4; ++j) lhist[t * 4 + j] = 0;
    __syncthreads();
    for (int i = s + t; i < e2; i += 256) {
        unsigned p = epack[i];
        int key = (int)((p >> 16) << 2) | (int)((p & 0xFFFFu) >> 14);
        atomicAdd(&lhist[key], 1);
    }
    __syncthreads();

    // thread t owns bins 4t..4t+3 (rows stay major-ordered)
    int h[4];
    int sl = 0;
    #pragma unroll
    for (int j = 0; j < 4; ++j) { h[j] = lhist[t * 4 + j]; sl += h[j]; }
    int total;
    int excl = block_excl_scan_256(sl, &total, wtot);

    int node = cb * 256 + t;
    deg[node]       = sl;             // row degree = sum of its 4 range bins
    row_start[node] = s + excl;
    int run = excl;
    #pragma unroll
    for (int j = 0; j < 4; ++j) { lbase[t * 4 + j] = run; run += h[j]; }
    __syncthreads();
    #pragma unroll
    for (int j = 0; j < 4; ++j) lhist[t * 4 + j] = 0;
    __syncthreads();

    for (int i = s + t; i < e2; i += 256) {
        unsigned p = epack[i];
        int col = (int)(p & 0xFFFFu);
        int key = (int)((p >> 16) << 2) | (col >> 14);
        int off = atomicAdd(&lhist[key], 1);
        sorted_col[s + lbase[key] + off] = col;
    }
}

// -------- 5. gather SPMM bf16: 16 lanes/node, 8-deep gather pipeline -------
__global__ __launch_bounds__(256) void spmm_gather_kernel(
    const short* __restrict__ src,
    const int*   __restrict__ row_start,
    const int*   __restrict__ sorted_col,
    short*       __restrict__ dst)
{
    int node = (blockIdx.x * 256 + threadIdx.x) >> 4;
    int lane = threadIdx.x & 15;
    if (node >= N_NODES) return;
    int s = row_start[node];
    int e = row_start[node + 1];

    float acc[8];
    #pragma unroll
    for (int j = 0; j < 8; ++j) acc[j] = 0.0f;

    for (int i = s; i < e; i += 8) {
        const int nn = e - i;
        int cidx[8];
        #pragma unroll
        for (int j = 0; j < 8; ++j)
            cidx[j] = sorted_col[i + (j < nn ? j : 0)];
        uint4 v[8];
        #pragma unroll
        for (int j = 0; j < 8; ++j)
            v[j] = *(const uint4*)(src + (size_t)cidx[j] * IN_DIM + lane * 8);
        #pragma unroll
        for (int j = 0; j < 8; ++j) {
            if (j < nn) {
                acc[0] += __uint_as_float(v[j].x << 16);
                acc[1] += __uint_as_float(v[j].x & 0xFFFF0000u);
                acc[2] += __uint_as_float(v[j].y << 16);
                acc[3] += __uint_as_float(v[j].y & 0xFFFF0000u);
                acc[4] += __uint_as_float(v[j].z << 16);
                acc[5] += __uint_as_float(v[j].z & 0xFFFF0000u);
                acc[6] += __uint_as_float(v[j].w << 16);
                acc[7] += __uint_as_float(v[j].w & 0xFFFF0000u);
            }
        }
    }
    bf16x8 r;
    #pragma unroll
    for (int j = 0; j < 8; ++j) r[j] = f2bf(acc[j]);
    *(bf16x8*)(dst + (size_t)node * IN_DIM + lane * 8) = r;
}

// -------- 6. fused dense: (x|ax|aax) @ Wt -> relu h (LDS) -> @ Wf -> out ---
// block bx: rows bx*64 .. +63. Per s: stage W-slice in LDS (stride 132),
// MFMA 16x16x32, epilogue (scale/bias/relu) -> h-tile in LDS (stride 296).
// Then 288->48 MFMA with Wf2t streamed from global (L2-hot), biased store.
// NOTE (R1 post-mortem): do NOT replace wbuf staging with global B-frag
// loads — that puts ~200 cy L2 latency on every MFMA (51 µs, MfmaUtil 3%).
#define HTS 296     // h-tile row stride in shorts (592 B, 16B-aligned)

__global__ __launch_bounds__(256) void dense_fused_kernel(
    const short* __restrict__ xbf,
    const short* __restrict__ axbf,
    const short* __restrict__ aaxbf,
    const int*   __restrict__ deg,
    const short* __restrict__ Wtbf,
    const short* __restrict__ Wf2t,
    const float* __restrict__ biasv,
    const float* __restrict__ bfin,
    float* __restrict__ out)
{
    __shared__ short wbuf[96 * 132];     // 25.3 KB weight slice
    __shared__ short htile[64 * HTS];    // 37.9 KB h tile

    const int tid  = threadIdx.x;
    const int w    = tid >> 6;
    const int lane = tid & 63;
    const int il   = lane & 15;
    const int kq   = lane >> 4;
    const int m0   = blockIdx.x * 64 + w * 16;

    // per-lane deg scales for the 4 output rows this lane owns
    float dvj[4];
    #pragma unroll
    for (int j = 0; j < 4; ++j) {
        int node = m0 + kq * 4 + j;
        dvj[j] = 1.0f / fmaxf((float)deg[node], 1.0f);
    }

    #pragma unroll
    for (int s = 0; s < 3; ++s) {
        // stage Wtbf slice s: 96 rows x 16 slots of 16B = 1536 uint4
        #pragma unroll
        for (int j = 0; j < 6; ++j) {
            int idx  = tid + j * 256;
            int brow = idx >> 4;
            int slot = idx & 15;
            uint4 v = *(const uint4*)(Wtbf + (size_t)(s * 96 + brow) * IN_DIM + slot * 8);
            *(uint4*)(wbuf + brow * 132 + slot * 8) = v;
        }
        __syncthreads();

        const short* __restrict__ src = (s == 0) ? xbf : (s == 1) ? axbf : aaxbf;
        const int arow = m0 + il;

        f32x4 acc[6];
        #pragma unroll
        for (int c = 0; c < 6; ++c)
            #pragma unroll
            for (int q = 0; q < 4; ++q) acc[c][q] = 0.0f;

        #pragma unroll
        for (int kk = 0; kk < 4; ++kk) {
            bf16x8 afrag = *(const bf16x8*)(
                src + (size_t)arow * IN_DIM + kk * 32 + kq * 8);
            #pragma unroll
            for (int c = 0; c < 6; ++c) {
                bf16x8 bfrag = *(const bf16x8*)(
                    wbuf + (c * 16 + il) * 132 + kk * 32 + kq * 8);
                acc[c] = __builtin_amdgcn_mfma_f32_16x16x32_bf16(
                    afrag, bfrag, acc[c], 0, 0, 0);
            }
        }

        #pragma unroll
        for (int j = 0; j < 4; ++j) {
            int nl = w * 16 + kq * 4 + j;          // row within block
            float sc = (s == 0) ? 1.0f : (s == 1) ? dvj[j] : dvj[j] * dvj[j];
            #pragma unroll
            for (int c = 0; c < 6; ++c) {
                int vcol = s * 96 + c * 16 + il;
                float hv = fmaf(acc[c][j], sc, biasv[vcol]);
                htile[nl * HTS + vcol] = f2bf(fmaxf(hv, 0.0f));
            }
        }
        __syncthreads();   // wbuf reads done before restage; htile visible at end
    }

    // second layer: htile (LDS) x Wf2t (global, 27.6 KB, L2-hot)
    f32x4 acc2[3];
    #pragma unroll
    for (int cc = 0; cc < 3; ++cc)
        #pragma unroll
        for (int q = 0; q < 4; ++q) acc2[cc][q] = 0.0f;

    #pragma unroll
    for (int kk = 0; kk < 9; ++kk) {
        bf16x8 afrag = *(const bf16x8*)(
            htile + (w * 16 + il) * HTS + kk * 32 + kq * 8);
        #pragma unroll
        for (int cc = 0; cc < 3; ++cc) {
            bf16x8 bfrag = *(const bf16x8*)(
                Wf2t + (size_t)(cc * 16 + il) * 288 + kk * 32 + kq * 8);
            acc2[cc] = __builtin_amdgcn_mfma_f32_16x16x32_bf16(
                afrag, bfrag, acc2[cc], 0, 0, 0);
        }
    }

    #pragma unroll
    for (int cc = 0; cc < 3; ++cc) {
        int colo = cc * 16 + il;
        if (colo < OUT_DIM) {
            float b = bfin[colo];
            #pragma unroll
            for (int j = 0; j < 4; ++j) {
                int node = m0 + kq * 4 + j;
                if (node < N_NODES)
                    out[(size_t)node * OUT_DIM + colo] = acc2[cc][j] + b;
            }
        }
    }
}

extern "C" void kernel_launch(void* const* d_in, const int* in_sizes, int n_in,
                              void* d_out, int out_size, void* d_ws, size_t ws_size,
                              hipStream_t stream)
{
    const float* x  = (const float*)d_in[0];
    const int*   ei = (const int*)  d_in[1];
    const float* W0 = (const float*)d_in[2];
    const float* b0 = (const float*)d_in[3];
    const float* W1 = (const float*)d_in[4];
    const float* b1 = (const float*)d_in[5];
    const float* W2 = (const float*)d_in[6];
    const float* b2 = (const float*)d_in[7];
    const float* Wf = (const float*)d_in[8];
    const float* bf = (const float*)d_in[9];
    float* out = (float*)d_out;

    const int* row = ei;
    const int* col = ei + E_EDGES;

    int* wsw = (int*)d_ws;
    int*          cnt        = wsw + OFF_CNT;
    int*          base       = wsw + OFF_BASE;
    int*          deg        = wsw + OFF_DEG;
    int*          row_start  = wsw + OFF_RS;
    unsigned int* epack      = (unsigned int*)(wsw + OFF_EPACK);
    int*          sorted_col = wsw + OFF_SCOL;
    short*        Wtbf       = (short*)(wsw + OFF_WTBF);
    short*        Wf2t       = (short*)(wsw + OFF_WF2T);
    float*        biasv      = (float*)(wsw + OFF_BV);
    short*        xbf        = (short*)(wsw + OFF_XBF);
    short*        axbf       = (short*)(wsw + OFF_AXBF);
    short*        aaxbf      = (short*)(wsw + OFF_AAXBF);
    int*          btot       = wsw + OFF_BTOT;
    int*          boff       = wsw + OFF_BOFF;
    (void)boff; (void)ws_size; (void)in_sizes; (void)n_in; (void)out_size;

    dim3 blk(256);
    prep_kernel          <<<3136 + NBLK + 200, blk, 0, stream>>>(
        x, xbf, row, cnt, W0, b0, W1, b1, W2, b2, Wf, Wtbf, Wf2t, biasv);
    scan_local_kernel    <<<NBKT, blk, 0, stream>>>(cnt, base, btot);
    scan_add_kernel      <<<NBKT, blk, 0, stream>>>(btot, base);
    scatter_coarse_kernel<<<NBLK, blk, 0, stream>>>(row, col, base, epack);
    fine_sort_kernel     <<<NBKT, blk, 0, stream>>>(epack, base, sorted_col,
                                                    deg, row_start);

    const int sg = (N_NODES * 16 + 255) / 256;
    spmm_gather_kernel<<<sg, blk, 0, stream>>>(xbf,  row_start, sorted_col, axbf);
    spmm_gather_kernel<<<sg, blk, 0, stream>>>(axbf, row_start, sorted_col, aaxbf);

    dense_fused_kernel<<<NPAD / 64, blk, 0, stream>>>(
        xbf, axbf, aaxbf, deg, Wtbf, Wf2t, biasv, bf, out);
}